// Round 12
// baseline (244.031 us; speedup 1.0000x reference)
//
#include <hip/hip_runtime.h>
#include <stdint.h>

#define BATCH 4
#define SEQ 2048
#define DMODEL 1024
#define NHEADS 16
#define HDIM 64
#define MROWS (BATCH * SEQ)   // 8192

typedef float floatx4 __attribute__((ext_vector_type(4)));
typedef __bf16 bf16x8 __attribute__((ext_vector_type(8)));
typedef __bf16 bf16x4 __attribute__((ext_vector_type(4)));
typedef short short8 __attribute__((ext_vector_type(8)));

__device__ __forceinline__ unsigned short f32_to_bf16(float f) {
    union { float f; unsigned int u; } c; c.f = f;
    unsigned int u = c.u;
    unsigned int r = (u + 0x7FFFu + ((u >> 16) & 1u)) >> 16;
    return (unsigned short)r;
}

// async global->LDS 16B per lane (m97 pattern; LDS dest must equal base + lane*16)
__device__ __forceinline__ void async_ld16(const void* g, void* l) {
    __builtin_amdgcn_global_load_lds(
        (const __attribute__((address_space(1))) unsigned int*)g,
        (__attribute__((address_space(3))) unsigned int*)l, 16, 0, 0);
}

// ---------------------------------------------------------------- fused prep
// One kernel replaces conv_f32_bf16 + 2x transp_conv (saves 2 launch gaps).
__global__ __launch_bounds__(256) void prep_kernel(
    const float* __restrict__ x, unsigned short* __restrict__ xb,
    const float* __restrict__ w_qkv, unsigned short* __restrict__ wqkvT,
    const float* __restrict__ w_proj, unsigned short* __restrict__ wprojT) {
    const int gx = blockIdx.x, gy = blockIdx.y;
    const int tx = threadIdx.x, ty = threadIdx.y;
    if (gx < 256) {
        int i = (gx * 32 + gy) * 256 + ty * 32 + tx;   // covers exactly MROWS*DMODEL/4
        float4 v = ((const float4*)x)[i];
        ushort4 o;
        o.x = f32_to_bf16(v.x); o.y = f32_to_bf16(v.y);
        o.z = f32_to_bf16(v.z); o.w = f32_to_bf16(v.w);
        ((ushort4*)xb)[i] = o;
        return;  // block-uniform path split
    }
    __shared__ float tile[32][33];
    const float* in; unsigned short* out; int N, bx;
    if (gx < 352) { in = w_qkv; out = wqkvT; N = 3072; bx = (gx - 256) * 32; }
    else          { in = w_proj; out = wprojT; N = 1024; bx = (gx - 352) * 32; }
    const int by = gy * 32;
#pragma unroll
    for (int i = 0; i < 4; ++i)
        tile[ty + i * 8][tx] = in[(size_t)(by + ty + i * 8) * N + bx + tx];
    __syncthreads();
#pragma unroll
    for (int i = 0; i < 4; ++i)
        out[(size_t)(bx + ty + i * 8) * DMODEL + by + tx] = f32_to_bf16(tile[tx][ty + i * 8]);
}

// ---------------------------------------------------------------- GEMM (B^T input)
// 3-buffer LDS, prefetch distance 2, counted vmcnt + raw barrier, T1 XCD swizzle.
// EPI==0 V-blocks (n0>=2048) write Vt DIRECTLY via an LDS transpose in the epilogue.
// EPI==1 output stored non-temporally (never re-read; stops it evicting the
// re-read wprojT/Yatt panels from L2 during proj).
template <int EPI>
__global__ __launch_bounds__(256, 3) void gemm_bt(
    const unsigned short* __restrict__ A, const unsigned short* __restrict__ Bt,
    const float* __restrict__ bias, float* __restrict__ Cout,
    unsigned short* __restrict__ Qo, unsigned short* __restrict__ Ko,
    unsigned short* __restrict__ Vo, int M, int N, int K) {
    __shared__ __align__(16) unsigned short SM[24576];  // 48KB: 3xA(8KB)+3xB(8KB) / V-tile
    const int tid = threadIdx.x;
    const int lane = tid & 63;
    const int w = tid >> 6;
    const int wm = w & 1, wn = w >> 1;
    const int quad = lane >> 4, l16 = lane & 15;

    // XCD-aware swizzle (contiguous chunk per XCD; bijective since nwg%8==0)
    const int nbx = gridDim.x;
    const int nwg = nbx * gridDim.y;
    const int lin = blockIdx.y * nbx + blockIdx.x;
    const int swz = (lin & 7) * (nwg >> 3) + (lin >> 3);
    const int m0 = (swz / nbx) * 128;
    const int n0 = (swz % nbx) * 128;
    const int fsw = (l16 >> 1) & 3;

    const int idx0 = tid, idx1 = tid + 256;
    const int row0 = idx0 >> 2, row1 = idx1 >> 2;
    const int cg0 = (idx0 & 3) ^ ((row0 >> 1) & 3);
    const int cg1 = (idx1 & 3) ^ ((row1 >> 1) & 3);
    const unsigned short* Ar0 = &A[(size_t)(m0 + row0) * K + cg0 * 8];
    const unsigned short* Ar1 = &A[(size_t)(m0 + row1) * K + cg1 * 8];
    const unsigned short* Br0 = &Bt[(size_t)(n0 + row0) * K + cg0 * 8];
    const unsigned short* Br1 = &Bt[(size_t)(n0 + row1) * K + cg1 * 8];

    floatx4 acc[4][4];
#pragma unroll
    for (int mt = 0; mt < 4; ++mt)
#pragma unroll
        for (int nt = 0; nt < 4; ++nt) acc[mt][nt] = (floatx4){0.f, 0.f, 0.f, 0.f};

    // prologue: tile 0 -> buf 0, tile 1 -> buf 1 (program order = vmcnt drain order)
    async_ld16(Ar0, &SM[idx0 * 8]);
    async_ld16(Br0, &SM[12288 + idx0 * 8]);
    async_ld16(Ar1, &SM[idx1 * 8]);
    async_ld16(Br1, &SM[12288 + idx1 * 8]);
    async_ld16(Ar0 + 32, &SM[4096 + idx0 * 8]);
    async_ld16(Br0 + 32, &SM[16384 + idx0 * 8]);
    async_ld16(Ar1 + 32, &SM[4096 + idx1 * 8]);
    async_ld16(Br1 + 32, &SM[16384 + idx1 * 8]);

    const int nk = K >> 5;
    int bcur = 0, bpre = 2;
    for (int kt = 0; kt < nk; ++kt) {
        if (kt + 2 < nk)
            asm volatile("s_waitcnt vmcnt(4)" ::: "memory");
        else
            asm volatile("s_waitcnt vmcnt(0)" ::: "memory");
        __builtin_amdgcn_s_barrier();
        asm volatile("" ::: "memory");  // pin prefetch + ds_reads below the barrier

        if (kt + 2 < nk) {  // prefetch distance 2, issued AFTER the barrier
            const int ko = (kt + 2) << 5;
            async_ld16(Ar0 + ko, &SM[bpre * 4096 + idx0 * 8]);
            async_ld16(Br0 + ko, &SM[12288 + bpre * 4096 + idx0 * 8]);
            async_ld16(Ar1 + ko, &SM[bpre * 4096 + idx1 * 8]);
            async_ld16(Br1 + ko, &SM[12288 + bpre * 4096 + idx1 * 8]);
        }

        bf16x8 aF[4], bF[4];
#pragma unroll
        for (int mt = 0; mt < 4; ++mt)
            aF[mt] = *(const bf16x8*)&SM[bcur * 4096 +
                                         (wm * 64 + mt * 16 + l16) * 32 + (quad ^ fsw) * 8];
#pragma unroll
        for (int nt = 0; nt < 4; ++nt)
            bF[nt] = *(const bf16x8*)&SM[12288 + bcur * 4096 +
                                         (wn * 64 + nt * 16 + l16) * 32 + (quad ^ fsw) * 8];
#pragma unroll
        for (int mt = 0; mt < 4; ++mt)
#pragma unroll
            for (int nt = 0; nt < 4; ++nt)
                acc[mt][nt] = __builtin_amdgcn_mfma_f32_16x16x32_bf16(
                    aF[mt], bF[nt], acc[mt][nt], 0, 0, 0);

        bcur = (bcur == 2) ? 0 : bcur + 1;
        bpre = (bpre == 2) ? 0 : bpre + 1;
    }

    if (EPI == 0 && n0 >= 2048) {
        // ---- V-block epilogue: fused transpose+permute via LDS -> Vt
        const int hbase = (n0 - 2048) >> 6;
        const int bb = m0 >> 11, t0 = m0 & 2047;
        __syncthreads();  // staging LDS dead (frags consumed; DMAs drained by last iters)
#pragma unroll
        for (int mt = 0; mt < 4; ++mt)
#pragma unroll
            for (int nt = 0; nt < 4; ++nt)
#pragma unroll
                for (int r = 0; r < 4; ++r) {
                    int tl = wm * 64 + mt * 16 + quad * 4 + r;
                    int nl = wn * 64 + nt * 16 + l16;
                    int c2 = (tl & 64) | ((tl & 15) << 2) | ((tl >> 4) & 3);
                    float v = acc[mt][nt][r] + bias[n0 + nl];
                    SM[nl * 132 + c2] = f32_to_bf16(v);
                }
        __syncthreads();
        const int rr = tid >> 1, hh = tid & 1;      // rr: (head,d) row; hh: t-half
        const int head = hbase + (rr >> 6), d = rr & 63;
        unsigned short* drow = Vo + ((size_t)(bb * NHEADS + head)) * SEQ * HDIM +
                               (size_t)d * SEQ + t0 + hh * 64;
        const unsigned short* srow = &SM[rr * 132 + hh * 64];
#pragma unroll
        for (int c = 0; c < 16; ++c)
            *(bf16x4*)&drow[c * 4] = *(const bf16x4*)&srow[c * 4];
        return;
    }

#pragma unroll
    for (int mt = 0; mt < 4; ++mt)
#pragma unroll
        for (int nt = 0; nt < 4; ++nt)
#pragma unroll
            for (int r = 0; r < 4; ++r) {
                int m = m0 + wm * 64 + mt * 16 + quad * 4 + r;
                int n = n0 + wn * 64 + nt * 16 + l16;
                float v = acc[mt][nt][r] + bias[n];
                if (EPI == 1) {
                    __builtin_nontemporal_store(v, &Cout[(size_t)m * N + n]);
                } else {
                    int sel = n >> 10, c = n & 1023;   // sel==2 handled above
                    int head = c >> 6, d = c & 63;
                    int bb = m >> 11, t = m & 2047;
                    unsigned short* dst = sel == 0 ? Qo : Ko;
                    dst[((((size_t)bb * NHEADS + head) * SEQ + t) << 6) + d] = f32_to_bf16(v);
                }
            }
}

// ---------------------------------------------------------------- flash attention v14
// (R10's best-measured version, restored after v15's fusion proved neutral-to-
// negative.) Merged mirror strips share one K/V loop (kmax = max(2by+2, 32-2by),
// wave-uniform per-strip skips); 3-buffer K/V, prefetch distance 2, counted
// vmcnt(4), raw barrier (never vmcnt(0) in steady state); T5 setprio around MFMA
// clusters (m191 regime: waves diverge via lastA/lastB). No VGPR cap (R7: the
// min-occupancy launch-bounds arg forces 84-VGPR spills). Grid 512 blocks = 2/CU;
// LDS 64KB keeps that occupancy (R9: occupancy is grid-capped, not LDS-capped).
__device__ __forceinline__ void strip_body(
    int kb, int rowb, int quad, int l16,
    const bf16x8 (&qf)[2][2], const unsigned short* Kb, const unsigned short* Vb,
    unsigned short* Pw, bf16x8 ones, float csc,
    floatx4 (&o)[2][4], floatx4 (&lsum)[2]) {
    // S = Q K^T
    floatx4 s[2][4];
#pragma unroll
    for (int mt = 0; mt < 2; ++mt)
#pragma unroll
        for (int nt = 0; nt < 4; ++nt) s[mt][nt] = (floatx4){0.f, 0.f, 0.f, 0.f};
#pragma unroll
    for (int kk = 0; kk < 2; ++kk) {
        bf16x8 kf[4];
#pragma unroll
        for (int nt = 0; nt < 4; ++nt)
            kf[nt] = *(const bf16x8*)&Kb[(nt * 16 + l16) * 64 +
                                         ((kk * 4 + quad) ^ (l16 & 7)) * 8];
        __builtin_amdgcn_s_setprio(1);
#pragma unroll
        for (int nt = 0; nt < 4; ++nt)
#pragma unroll
            for (int mt = 0; mt < 2; ++mt)
                s[mt][nt] = __builtin_amdgcn_mfma_f32_16x16x32_bf16(
                    qf[mt][kk], kf[nt], s[mt][nt], 0, 0, 0);
        __builtin_amdgcn_s_setprio(0);
    }

    if ((kb * 64 + 63) > rowb) {  // wave-uniform diagonal mask
#pragma unroll
        for (int mt = 0; mt < 2; ++mt)
#pragma unroll
            for (int nt = 0; nt < 4; ++nt)
#pragma unroll
                for (int r = 0; r < 4; ++r) {
                    int key = kb * 64 + nt * 16 + l16;
                    int qrow = rowb + mt * 16 + quad * 4 + r;
                    if (key > qrow) s[mt][nt][r] = -INFINITY;
                }
    }

    // p = exp2(score * 0.125*log2e) == exp(score/8); no max subtraction
#pragma unroll
    for (int mt = 0; mt < 2; ++mt)
#pragma unroll
        for (int nt = 0; nt < 4; ++nt)
#pragma unroll
            for (int r = 0; r < 4; ++r)
                s[mt][nt][r] = __builtin_amdgcn_exp2f(s[mt][nt][r] * csc);

    // P -> per-wave LDS, packed slots k2 = l16*4+nt; swizzled by (prow&14)
#pragma unroll
    for (int mt = 0; mt < 2; ++mt)
#pragma unroll
        for (int r = 0; r < 4; ++r) {
            int prow = mt * 16 + quad * 4 + r;
            int unit = l16 ^ (prow & 14);
            floatx4 t = {s[mt][0][r], s[mt][1][r], s[mt][2][r], s[mt][3][r]};
            bf16x4 pv = __builtin_convertvector(t, bf16x4);
            *(bf16x4*)&Pw[prow * 64 + unit * 4] = pv;
        }

    // O += P V ; l += P 1   (V^T pre-permuted to packed key order)
#pragma unroll
    for (int kk = 0; kk < 2; ++kk) {
        bf16x8 af[2];
#pragma unroll
        for (int mt = 0; mt < 2; ++mt) {
            int prow = mt * 16 + l16;
            int u2 = (kk * 8 + quad * 2) ^ (l16 & 14);
            af[mt] = *(const bf16x8*)&Pw[prow * 64 + u2 * 4];
        }
        bf16x8 vf[4];
#pragma unroll
        for (int nt = 0; nt < 4; ++nt)
            vf[nt] = *(const bf16x8*)&Vb[(nt * 16 + l16) * 64 +
                                         ((kk * 4 + quad) ^ (l16 & 7)) * 8];
        __builtin_amdgcn_s_setprio(1);
#pragma unroll
        for (int nt = 0; nt < 4; ++nt)
#pragma unroll
            for (int mt = 0; mt < 2; ++mt)
                o[mt][nt] = __builtin_amdgcn_mfma_f32_16x16x32_bf16(
                    af[mt], vf[nt], o[mt][nt], 0, 0, 0);
#pragma unroll
        for (int mt = 0; mt < 2; ++mt)
            lsum[mt] = __builtin_amdgcn_mfma_f32_16x16x32_bf16(
                af[mt], ones, lsum[mt], 0, 0, 0);
        __builtin_amdgcn_s_setprio(0);
    }
}

__global__ __launch_bounds__(256, 2) void attn_kernel(
    const unsigned short* __restrict__ Qg, const unsigned short* __restrict__ Kg,
    const unsigned short* __restrict__ Vtg, unsigned short* __restrict__ Yatt) {
    __shared__ __align__(16) unsigned short Kb2[3][4096];  // [buf][key][d]   8KB each
    __shared__ __align__(16) unsigned short Vb2[3][4096];  // [buf][d][key~]  8KB each
    __shared__ __align__(16) unsigned short Ps[4][2048];   // per-wave packed P

    const int tid = threadIdx.x;
    const int lane = tid & 63;
    const int w = tid >> 6;
    const int quad = lane >> 4, l16 = lane & 15;
    const int bh = blockIdx.x;           // 0..63 -> XCD bh%8 (L2 locality: all 8
    const int by = blockIdx.y;           //   by-blocks of a bh land on one XCD)
    const int sA = by * 4 + w;           // strip 0..31 (mirror = 63-sA)
    const size_t base = (size_t)bh * SEQ * HDIM;
    const int bIdx = bh >> 4, h = bh & 15;
    unsigned short* Pw = &Ps[w][0];
    const float csc = 0.18033688f;  // 0.125 * log2(e)

    const int lrow = lane >> 3;                 // 0..7 within a DMA instr
    const int lch = (lane & 7) ^ lrow;          // source chunk (store-swizzle ^ row&7)

    short8 osv = {0x3F80, 0x3F80, 0x3F80, 0x3F80, 0x3F80, 0x3F80, 0x3F80, 0x3F80};
    bf16x8 ones = __builtin_bit_cast(bf16x8, osv);

    const int rowbA = sA * 32;
    const int rowbB = (63 - sA) * 32;
    const int tA = 2 * by + 2, tB = 32 - 2 * by;
    const int kmaxB = tA > tB ? tA : tB;        // block-uniform, 18..32
    const int lastA = sA >> 1;                  // strip A computes kb <= lastA
    const int lastB = (2047 - 32 * sA) >> 6;    // strip B computes kb <= lastB

    const unsigned short* Ktg = Kg + base;
    const unsigned short* Vtg_t = Vtg + base;
    const int i0 = w * 2, i1 = w * 2 + 1;
    const int kof0 = (i0 * 8 + lrow) * 64 + lch * 8;
    const int kof1 = (i1 * 8 + lrow) * 64 + lch * 8;
    const size_t vof0 = (size_t)(i0 * 8 + lrow) * SEQ + lch * 8;
    const size_t vof1 = (size_t)(i1 * 8 + lrow) * SEQ + lch * 8;
    const int ld0 = i0 * 512 + lane * 8;
    const int ld1 = i1 * 512 + lane * 8;

    // Q fragments for BOTH strips -> registers
    bf16x8 qfA[2][2], qfB[2][2];
#pragma unroll
    for (int mt = 0; mt < 2; ++mt)
#pragma unroll
        for (int kk = 0; kk < 2; ++kk) {
            qfA[mt][kk] = *(const bf16x8*)&Qg[base + (size_t)(rowbA + mt * 16 + l16) * 64 +
                                              kk * 32 + quad * 8];
            qfB[mt][kk] = *(const bf16x8*)&Qg[base + (size_t)(rowbB + mt * 16 + l16) * 64 +
                                              kk * 32 + quad * 8];
        }
    asm volatile("" ::: "memory");  // keep Q loads above the staging DMAs

    floatx4 lsumA[2], lsumB[2];
    floatx4 oA[2][4], oB[2][4];
#pragma unroll
    for (int mt = 0; mt < 2; ++mt) {
        lsumA[mt] = (floatx4){0.f, 0.f, 0.f, 0.f};
        lsumB[mt] = (floatx4){0.f, 0.f, 0.f, 0.f};
#pragma unroll
        for (int nt = 0; nt < 4; ++nt) {
            oA[mt][nt] = (floatx4){0.f, 0.f, 0.f, 0.f};
            oB[mt][nt] = (floatx4){0.f, 0.f, 0.f, 0.f};
        }
    }

    // prologue: tile 0 -> buf 0, tile 1 -> buf 1 (kmaxB >= 18 always)
    async_ld16(Ktg + kof0, &Kb2[0][ld0]);
    async_ld16(Vtg_t + vof0, &Vb2[0][ld0]);
    async_ld16(Ktg + kof1, &Kb2[0][ld1]);
    async_ld16(Vtg_t + vof1, &Vb2[0][ld1]);
    async_ld16(Ktg + 64 * HDIM + kof0, &Kb2[1][ld0]);
    async_ld16(Vtg_t + 64 + vof0, &Vb2[1][ld0]);
    async_ld16(Ktg + 64 * HDIM + kof1, &Kb2[1][ld1]);
    async_ld16(Vtg_t + 64 + vof1, &Vb2[1][ld1]);

    int bcur = 0, bpre = 2;
    for (int kb = 0; kb < kmaxB; ++kb) {
        if (kb + 2 < kmaxB)
            asm volatile("s_waitcnt vmcnt(4)" ::: "memory");
        else
            asm volatile("s_waitcnt vmcnt(0)" ::: "memory");
        __builtin_amdgcn_s_barrier();
        asm volatile("" ::: "memory");

        if (kb + 2 < kmaxB) {  // prefetch distance 2, AFTER the barrier
            const unsigned short* Kt2 = Ktg + (size_t)(kb + 2) * 64 * HDIM;
            const unsigned short* Vt2 = Vtg_t + (kb + 2) * 64;
            async_ld16(Kt2 + kof0, &Kb2[bpre][ld0]);
            async_ld16(Vt2 + vof0, &Vb2[bpre][ld0]);
            async_ld16(Kt2 + kof1, &Kb2[bpre][ld1]);
            async_ld16(Vt2 + vof1, &Vb2[bpre][ld1]);
        }

        // strip A then strip B share the staged tile; per-wave P-LDS buffer is
        // reused sequentially (compiler orders the intra-wave LDS accesses).
        if (kb <= lastA)
            strip_body(kb, rowbA, quad, l16, qfA, &Kb2[bcur][0], &Vb2[bcur][0],
                       Pw, ones, csc, oA, lsumA);
        if (kb <= lastB)
            strip_body(kb, rowbB, quad, l16, qfB, &Kb2[bcur][0], &Vb2[bcur][0],
                       Pw, ones, csc, oB, lsumB);

        bcur = (bcur == 2) ? 0 : bcur + 1;
        bpre = (bpre == 2) ? 0 : bpre + 1;
    }

    // epilogue: both strips
#pragma unroll
    for (int mt = 0; mt < 2; ++mt)
#pragma unroll
        for (int r = 0; r < 4; ++r) {
            float invA = 1.0f / lsumA[mt][r];
            float invB = 1.0f / lsumB[mt][r];
            int qrowA = rowbA + mt * 16 + quad * 4 + r;
            int qrowB = rowbB + mt * 16 + quad * 4 + r;
#pragma unroll
            for (int nt = 0; nt < 4; ++nt) {
                Yatt[((size_t)(bIdx * SEQ + qrowA) << 10) + h * 64 + nt * 16 + l16] =
                    f32_to_bf16(oA[mt][nt][r] * invA);
                Yatt[((size_t)(bIdx * SEQ + qrowB) << 10) + h * 64 + nt * 16 + l16] =
                    f32_to_bf16(oB[mt][nt][r] * invB);
            }
        }
}

// ---------------------------------------------------------------- launch
extern "C" void kernel_launch(void* const* d_in, const int* in_sizes, int n_in,
                              void* d_out, int out_size, void* d_ws, size_t ws_size,
                              hipStream_t stream) {
    const float* x = (const float*)d_in[0];
    const float* w_qkv = (const float*)d_in[1];
    const float* b_qkv = (const float*)d_in[2];
    const float* w_proj = (const float*)d_in[3];
    const float* b_proj = (const float*)d_in[4];
    float* out = (float*)d_out;

    char* ws = (char*)d_ws;
    unsigned short* xb     = (unsigned short*)(ws);                       // 16 MB
    unsigned short* wqkvT  = (unsigned short*)(ws + 16777216);            // 6 MB
    unsigned short* wprojT = (unsigned short*)(ws + 23068672);            // 2 MB
    unsigned short* Qb     = (unsigned short*)(ws + 25165824);            // 16 MB
    unsigned short* Kb     = (unsigned short*)(ws + 41943040);            // 16 MB
    unsigned short* Yatt   = (unsigned short*)(ws + 75497472);            // 16 MB
    unsigned short* Vt     = (unsigned short*)(ws + 92274688);            // 16 MB

    prep_kernel<<<dim3(384, 32), dim3(32, 8), 0, stream>>>(x, xb, w_qkv, wqkvT,
                                                           w_proj, wprojT);
    gemm_bt<0><<<dim3(24, 64), 256, 0, stream>>>(xb, wqkvT, b_qkv, nullptr, Qb, Kb, Vt,
                                                 MROWS, 3 * DMODEL, DMODEL);
    attn_kernel<<<dim3(64, 8), 256, 0, stream>>>(Qb, Kb, Vt, Yatt);
    gemm_bt<1><<<dim3(8, 64), 256, 0, stream>>>(Yatt, wprojT, b_proj, out, nullptr, nullptr,
                                                nullptr, MROWS, DMODEL, DMODEL);
}

// Round 13
// 235.761 us; speedup vs baseline: 1.0351x; 1.0351x over previous
//
#include <hip/hip_runtime.h>
#include <stdint.h>

#define BATCH 4
#define SEQ 2048
#define DMODEL 1024
#define NHEADS 16
#define HDIM 64
#define MROWS (BATCH * SEQ)   // 8192

typedef float floatx4 __attribute__((ext_vector_type(4)));
typedef __bf16 bf16x8 __attribute__((ext_vector_type(8)));
typedef __bf16 bf16x4 __attribute__((ext_vector_type(4)));
typedef short short8 __attribute__((ext_vector_type(8)));

__device__ __forceinline__ unsigned short f32_to_bf16(float f) {
    union { float f; unsigned int u; } c; c.f = f;
    unsigned int u = c.u;
    unsigned int r = (u + 0x7FFFu + ((u >> 16) & 1u)) >> 16;
    return (unsigned short)r;
}

// async global->LDS 16B per lane (m97 pattern; LDS dest must equal base + lane*16)
__device__ __forceinline__ void async_ld16(const void* g, void* l) {
    __builtin_amdgcn_global_load_lds(
        (const __attribute__((address_space(1))) unsigned int*)g,
        (__attribute__((address_space(3))) unsigned int*)l, 16, 0, 0);
}

// ---------------------------------------------------------------- fused prep
// One kernel replaces conv_f32_bf16 + 2x transp_conv (saves 2 launch gaps).
__global__ __launch_bounds__(256) void prep_kernel(
    const float* __restrict__ x, unsigned short* __restrict__ xb,
    const float* __restrict__ w_qkv, unsigned short* __restrict__ wqkvT,
    const float* __restrict__ w_proj, unsigned short* __restrict__ wprojT) {
    const int gx = blockIdx.x, gy = blockIdx.y;
    const int tx = threadIdx.x, ty = threadIdx.y;
    if (gx < 256) {
        int i = (gx * 32 + gy) * 256 + ty * 32 + tx;   // covers exactly MROWS*DMODEL/4
        float4 v = ((const float4*)x)[i];
        ushort4 o;
        o.x = f32_to_bf16(v.x); o.y = f32_to_bf16(v.y);
        o.z = f32_to_bf16(v.z); o.w = f32_to_bf16(v.w);
        ((ushort4*)xb)[i] = o;
        return;  // block-uniform path split
    }
    __shared__ float tile[32][33];
    const float* in; unsigned short* out; int N, bx;
    if (gx < 352) { in = w_qkv; out = wqkvT; N = 3072; bx = (gx - 256) * 32; }
    else          { in = w_proj; out = wprojT; N = 1024; bx = (gx - 352) * 32; }
    const int by = gy * 32;
#pragma unroll
    for (int i = 0; i < 4; ++i)
        tile[ty + i * 8][tx] = in[(size_t)(by + ty + i * 8) * N + bx + tx];
    __syncthreads();
#pragma unroll
    for (int i = 0; i < 4; ++i)
        out[(size_t)(bx + ty + i * 8) * DMODEL + by + tx] = f32_to_bf16(tile[tx][ty + i * 8]);
}

// ---------------------------------------------------------------- GEMM (B^T input)
// 3-buffer LDS, prefetch distance 2, counted vmcnt + raw barrier, T1 XCD swizzle.
// EPI==0 V-blocks (n0>=2048) write Vt DIRECTLY via an LDS transpose in the epilogue.
template <int EPI>
__global__ __launch_bounds__(256, 3) void gemm_bt(
    const unsigned short* __restrict__ A, const unsigned short* __restrict__ Bt,
    const float* __restrict__ bias, float* __restrict__ Cout,
    unsigned short* __restrict__ Qo, unsigned short* __restrict__ Ko,
    unsigned short* __restrict__ Vo, int M, int N, int K) {
    __shared__ __align__(16) unsigned short SM[24576];  // 48KB: 3xA(8KB)+3xB(8KB) / V-tile
    const int tid = threadIdx.x;
    const int lane = tid & 63;
    const int w = tid >> 6;
    const int wm = w & 1, wn = w >> 1;
    const int quad = lane >> 4, l16 = lane & 15;

    // XCD-aware swizzle (contiguous chunk per XCD; bijective since nwg%8==0)
    const int nbx = gridDim.x;
    const int nwg = nbx * gridDim.y;
    const int lin = blockIdx.y * nbx + blockIdx.x;
    const int swz = (lin & 7) * (nwg >> 3) + (lin >> 3);
    const int m0 = (swz / nbx) * 128;
    const int n0 = (swz % nbx) * 128;
    const int fsw = (l16 >> 1) & 3;

    const int idx0 = tid, idx1 = tid + 256;
    const int row0 = idx0 >> 2, row1 = idx1 >> 2;
    const int cg0 = (idx0 & 3) ^ ((row0 >> 1) & 3);
    const int cg1 = (idx1 & 3) ^ ((row1 >> 1) & 3);
    const unsigned short* Ar0 = &A[(size_t)(m0 + row0) * K + cg0 * 8];
    const unsigned short* Ar1 = &A[(size_t)(m0 + row1) * K + cg1 * 8];
    const unsigned short* Br0 = &Bt[(size_t)(n0 + row0) * K + cg0 * 8];
    const unsigned short* Br1 = &Bt[(size_t)(n0 + row1) * K + cg1 * 8];

    floatx4 acc[4][4];
#pragma unroll
    for (int mt = 0; mt < 4; ++mt)
#pragma unroll
        for (int nt = 0; nt < 4; ++nt) acc[mt][nt] = (floatx4){0.f, 0.f, 0.f, 0.f};

    // prologue: tile 0 -> buf 0, tile 1 -> buf 1 (program order = vmcnt drain order)
    async_ld16(Ar0, &SM[idx0 * 8]);
    async_ld16(Br0, &SM[12288 + idx0 * 8]);
    async_ld16(Ar1, &SM[idx1 * 8]);
    async_ld16(Br1, &SM[12288 + idx1 * 8]);
    async_ld16(Ar0 + 32, &SM[4096 + idx0 * 8]);
    async_ld16(Br0 + 32, &SM[16384 + idx0 * 8]);
    async_ld16(Ar1 + 32, &SM[4096 + idx1 * 8]);
    async_ld16(Br1 + 32, &SM[16384 + idx1 * 8]);

    const int nk = K >> 5;
    int bcur = 0, bpre = 2;
    for (int kt = 0; kt < nk; ++kt) {
        if (kt + 2 < nk)
            asm volatile("s_waitcnt vmcnt(4)" ::: "memory");
        else
            asm volatile("s_waitcnt vmcnt(0)" ::: "memory");
        __builtin_amdgcn_s_barrier();
        asm volatile("" ::: "memory");  // pin prefetch + ds_reads below the barrier

        if (kt + 2 < nk) {  // prefetch distance 2, issued AFTER the barrier
            const int ko = (kt + 2) << 5;
            async_ld16(Ar0 + ko, &SM[bpre * 4096 + idx0 * 8]);
            async_ld16(Br0 + ko, &SM[12288 + bpre * 4096 + idx0 * 8]);
            async_ld16(Ar1 + ko, &SM[bpre * 4096 + idx1 * 8]);
            async_ld16(Br1 + ko, &SM[12288 + bpre * 4096 + idx1 * 8]);
        }

        bf16x8 aF[4], bF[4];
#pragma unroll
        for (int mt = 0; mt < 4; ++mt)
            aF[mt] = *(const bf16x8*)&SM[bcur * 4096 +
                                         (wm * 64 + mt * 16 + l16) * 32 + (quad ^ fsw) * 8];
#pragma unroll
        for (int nt = 0; nt < 4; ++nt)
            bF[nt] = *(const bf16x8*)&SM[12288 + bcur * 4096 +
                                         (wn * 64 + nt * 16 + l16) * 32 + (quad ^ fsw) * 8];
#pragma unroll
        for (int mt = 0; mt < 4; ++mt)
#pragma unroll
            for (int nt = 0; nt < 4; ++nt)
                acc[mt][nt] = __builtin_amdgcn_mfma_f32_16x16x32_bf16(
                    aF[mt], bF[nt], acc[mt][nt], 0, 0, 0);

        bcur = (bcur == 2) ? 0 : bcur + 1;
        bpre = (bpre == 2) ? 0 : bpre + 1;
    }

    if (EPI == 0 && n0 >= 2048) {
        // ---- V-block epilogue: fused transpose+permute via LDS -> Vt
        const int hbase = (n0 - 2048) >> 6;
        const int bb = m0 >> 11, t0 = m0 & 2047;
        __syncthreads();  // staging LDS dead (frags consumed; DMAs drained by last iters)
#pragma unroll
        for (int mt = 0; mt < 4; ++mt)
#pragma unroll
            for (int nt = 0; nt < 4; ++nt)
#pragma unroll
                for (int r = 0; r < 4; ++r) {
                    int tl = wm * 64 + mt * 16 + quad * 4 + r;
                    int nl = wn * 64 + nt * 16 + l16;
                    int c2 = (tl & 64) | ((tl & 15) << 2) | ((tl >> 4) & 3);
                    float v = acc[mt][nt][r] + bias[n0 + nl];
                    SM[nl * 132 + c2] = f32_to_bf16(v);
                }
        __syncthreads();
        const int rr = tid >> 1, hh = tid & 1;      // rr: (head,d) row; hh: t-half
        const int head = hbase + (rr >> 6), d = rr & 63;
        unsigned short* drow = Vo + ((size_t)(bb * NHEADS + head)) * SEQ * HDIM +
                               (size_t)d * SEQ + t0 + hh * 64;
        const unsigned short* srow = &SM[rr * 132 + hh * 64];
#pragma unroll
        for (int c = 0; c < 16; ++c)
            *(bf16x4*)&drow[c * 4] = *(const bf16x4*)&srow[c * 4];
        return;
    }

#pragma unroll
    for (int mt = 0; mt < 4; ++mt)
#pragma unroll
        for (int nt = 0; nt < 4; ++nt)
#pragma unroll
            for (int r = 0; r < 4; ++r) {
                int m = m0 + wm * 64 + mt * 16 + quad * 4 + r;
                int n = n0 + wn * 64 + nt * 16 + l16;
                float v = acc[mt][nt][r] + bias[n];
                if (EPI == 1) {
                    Cout[(size_t)m * N + n] = v;
                } else {
                    int sel = n >> 10, c = n & 1023;   // sel==2 handled above
                    int head = c >> 6, d = c & 63;
                    int bb = m >> 11, t = m & 2047;
                    unsigned short* dst = sel == 0 ? Qo : Ko;
                    dst[((((size_t)bb * NHEADS + head) * SEQ + t) << 6) + d] = f32_to_bf16(v);
                }
            }
}

// ---------------------------------------------------------------- flash attention v14
// (Best-measured version: 236.12us total at R10.) Merged mirror strips share one
// K/V loop (kmax = max(2by+2, 32-2by), wave-uniform per-strip skips); 3-buffer K/V,
// prefetch distance 2, counted vmcnt(4), raw barrier (never vmcnt(0) in steady
// state); T5 setprio around MFMA clusters. No VGPR cap (R7: min-occupancy
// launch-bounds arg forces 84-VGPR spills). Grid 512 blocks = 2/CU (R9 lesson:
// occupancy is grid-capped, not LDS-capped).
__device__ __forceinline__ void strip_body(
    int kb, int rowb, int quad, int l16,
    const bf16x8 (&qf)[2][2], const unsigned short* Kb, const unsigned short* Vb,
    unsigned short* Pw, bf16x8 ones, float csc,
    floatx4 (&o)[2][4], floatx4 (&lsum)[2]) {
    // S = Q K^T
    floatx4 s[2][4];
#pragma unroll
    for (int mt = 0; mt < 2; ++mt)
#pragma unroll
        for (int nt = 0; nt < 4; ++nt) s[mt][nt] = (floatx4){0.f, 0.f, 0.f, 0.f};
#pragma unroll
    for (int kk = 0; kk < 2; ++kk) {
        bf16x8 kf[4];
#pragma unroll
        for (int nt = 0; nt < 4; ++nt)
            kf[nt] = *(const bf16x8*)&Kb[(nt * 16 + l16) * 64 +
                                         ((kk * 4 + quad) ^ (l16 & 7)) * 8];
        __builtin_amdgcn_s_setprio(1);
#pragma unroll
        for (int nt = 0; nt < 4; ++nt)
#pragma unroll
            for (int mt = 0; mt < 2; ++mt)
                s[mt][nt] = __builtin_amdgcn_mfma_f32_16x16x32_bf16(
                    qf[mt][kk], kf[nt], s[mt][nt], 0, 0, 0);
        __builtin_amdgcn_s_setprio(0);
    }

    if ((kb * 64 + 63) > rowb) {  // wave-uniform diagonal mask
#pragma unroll
        for (int mt = 0; mt < 2; ++mt)
#pragma unroll
            for (int nt = 0; nt < 4; ++nt)
#pragma unroll
                for (int r = 0; r < 4; ++r) {
                    int key = kb * 64 + nt * 16 + l16;
                    int qrow = rowb + mt * 16 + quad * 4 + r;
                    if (key > qrow) s[mt][nt][r] = -INFINITY;
                }
    }

    // p = exp2(score * 0.125*log2e) == exp(score/8); no max subtraction
#pragma unroll
    for (int mt = 0; mt < 2; ++mt)
#pragma unroll
        for (int nt = 0; nt < 4; ++nt)
#pragma unroll
            for (int r = 0; r < 4; ++r)
                s[mt][nt][r] = __builtin_amdgcn_exp2f(s[mt][nt][r] * csc);

    // P -> per-wave LDS, packed slots k2 = l16*4+nt; swizzled by (prow&14)
#pragma unroll
    for (int mt = 0; mt < 2; ++mt)
#pragma unroll
        for (int r = 0; r < 4; ++r) {
            int prow = mt * 16 + quad * 4 + r;
            int unit = l16 ^ (prow & 14);
            floatx4 t = {s[mt][0][r], s[mt][1][r], s[mt][2][r], s[mt][3][r]};
            bf16x4 pv = __builtin_convertvector(t, bf16x4);
            *(bf16x4*)&Pw[prow * 64 + unit * 4] = pv;
        }

    // O += P V ; l += P 1   (V^T pre-permuted to packed key order)
#pragma unroll
    for (int kk = 0; kk < 2; ++kk) {
        bf16x8 af[2];
#pragma unroll
        for (int mt = 0; mt < 2; ++mt) {
            int prow = mt * 16 + l16;
            int u2 = (kk * 8 + quad * 2) ^ (l16 & 14);
            af[mt] = *(const bf16x8*)&Pw[prow * 64 + u2 * 4];
        }
        bf16x8 vf[4];
#pragma unroll
        for (int nt = 0; nt < 4; ++nt)
            vf[nt] = *(const bf16x8*)&Vb[(nt * 16 + l16) * 64 +
                                         ((kk * 4 + quad) ^ (l16 & 7)) * 8];
        __builtin_amdgcn_s_setprio(1);
#pragma unroll
        for (int nt = 0; nt < 4; ++nt)
#pragma unroll
            for (int mt = 0; mt < 2; ++mt)
                o[mt][nt] = __builtin_amdgcn_mfma_f32_16x16x32_bf16(
                    af[mt], vf[nt], o[mt][nt], 0, 0, 0);
#pragma unroll
        for (int mt = 0; mt < 2; ++mt)
            lsum[mt] = __builtin_amdgcn_mfma_f32_16x16x32_bf16(
                af[mt], ones, lsum[mt], 0, 0, 0);
        __builtin_amdgcn_s_setprio(0);
    }
}

__global__ __launch_bounds__(256, 2) void attn_kernel(
    const unsigned short* __restrict__ Qg, const unsigned short* __restrict__ Kg,
    const unsigned short* __restrict__ Vtg, unsigned short* __restrict__ Yatt) {
    __shared__ __align__(16) unsigned short Kb2[3][4096];  // [buf][key][d]   8KB each
    __shared__ __align__(16) unsigned short Vb2[3][4096];  // [buf][d][key~]  8KB each
    __shared__ __align__(16) unsigned short Ps[4][2048];   // per-wave packed P

    const int tid = threadIdx.x;
    const int lane = tid & 63;
    const int w = tid >> 6;
    const int quad = lane >> 4, l16 = lane & 15;
    const int bh = blockIdx.x;           // 0..63 -> XCD bh%8 (L2 locality: all 8
    const int by = blockIdx.y;           //   by-blocks of a bh land on one XCD)
    const int sA = by * 4 + w;           // strip 0..31 (mirror = 63-sA)
    const size_t base = (size_t)bh * SEQ * HDIM;
    const int bIdx = bh >> 4, h = bh & 15;
    unsigned short* Pw = &Ps[w][0];
    const float csc = 0.18033688f;  // 0.125 * log2(e)

    const int lrow = lane >> 3;                 // 0..7 within a DMA instr
    const int lch = (lane & 7) ^ lrow;          // source chunk (store-swizzle ^ row&7)

    short8 osv = {0x3F80, 0x3F80, 0x3F80, 0x3F80, 0x3F80, 0x3F80, 0x3F80, 0x3F80};
    bf16x8 ones = __builtin_bit_cast(bf16x8, osv);

    const int rowbA = sA * 32;
    const int rowbB = (63 - sA) * 32;
    const int tA = 2 * by + 2, tB = 32 - 2 * by;
    const int kmaxB = tA > tB ? tA : tB;        // block-uniform, 18..32
    const int lastA = sA >> 1;                  // strip A computes kb <= lastA
    const int lastB = (2047 - 32 * sA) >> 6;    // strip B computes kb <= lastB

    const unsigned short* Ktg = Kg + base;
    const unsigned short* Vtg_t = Vtg + base;
    const int i0 = w * 2, i1 = w * 2 + 1;
    const int kof0 = (i0 * 8 + lrow) * 64 + lch * 8;
    const int kof1 = (i1 * 8 + lrow) * 64 + lch * 8;
    const size_t vof0 = (size_t)(i0 * 8 + lrow) * SEQ + lch * 8;
    const size_t vof1 = (size_t)(i1 * 8 + lrow) * SEQ + lch * 8;
    const int ld0 = i0 * 512 + lane * 8;
    const int ld1 = i1 * 512 + lane * 8;

    // Q fragments for BOTH strips -> registers
    bf16x8 qfA[2][2], qfB[2][2];
#pragma unroll
    for (int mt = 0; mt < 2; ++mt)
#pragma unroll
        for (int kk = 0; kk < 2; ++kk) {
            qfA[mt][kk] = *(const bf16x8*)&Qg[base + (size_t)(rowbA + mt * 16 + l16) * 64 +
                                              kk * 32 + quad * 8];
            qfB[mt][kk] = *(const bf16x8*)&Qg[base + (size_t)(rowbB + mt * 16 + l16) * 64 +
                                              kk * 32 + quad * 8];
        }
    asm volatile("" ::: "memory");  // keep Q loads above the staging DMAs

    floatx4 lsumA[2], lsumB[2];
    floatx4 oA[2][4], oB[2][4];
#pragma unroll
    for (int mt = 0; mt < 2; ++mt) {
        lsumA[mt] = (floatx4){0.f, 0.f, 0.f, 0.f};
        lsumB[mt] = (floatx4){0.f, 0.f, 0.f, 0.f};
#pragma unroll
        for (int nt = 0; nt < 4; ++nt) {
            oA[mt][nt] = (floatx4){0.f, 0.f, 0.f, 0.f};
            oB[mt][nt] = (floatx4){0.f, 0.f, 0.f, 0.f};
        }
    }

    // prologue: tile 0 -> buf 0, tile 1 -> buf 1 (kmaxB >= 18 always)
    async_ld16(Ktg + kof0, &Kb2[0][ld0]);
    async_ld16(Vtg_t + vof0, &Vb2[0][ld0]);
    async_ld16(Ktg + kof1, &Kb2[0][ld1]);
    async_ld16(Vtg_t + vof1, &Vb2[0][ld1]);
    async_ld16(Ktg + 64 * HDIM + kof0, &Kb2[1][ld0]);
    async_ld16(Vtg_t + 64 + vof0, &Vb2[1][ld0]);
    async_ld16(Ktg + 64 * HDIM + kof1, &Kb2[1][ld1]);
    async_ld16(Vtg_t + 64 + vof1, &Vb2[1][ld1]);

    int bcur = 0, bpre = 2;
    for (int kb = 0; kb < kmaxB; ++kb) {
        if (kb + 2 < kmaxB)
            asm volatile("s_waitcnt vmcnt(4)" ::: "memory");
        else
            asm volatile("s_waitcnt vmcnt(0)" ::: "memory");
        __builtin_amdgcn_s_barrier();
        asm volatile("" ::: "memory");

        if (kb + 2 < kmaxB) {  // prefetch distance 2, AFTER the barrier
            const unsigned short* Kt2 = Ktg + (size_t)(kb + 2) * 64 * HDIM;
            const unsigned short* Vt2 = Vtg_t + (kb + 2) * 64;
            async_ld16(Kt2 + kof0, &Kb2[bpre][ld0]);
            async_ld16(Vt2 + vof0, &Vb2[bpre][ld0]);
            async_ld16(Kt2 + kof1, &Kb2[bpre][ld1]);
            async_ld16(Vt2 + vof1, &Vb2[bpre][ld1]);
        }

        // strip A then strip B share the staged tile; per-wave P-LDS buffer is
        // reused sequentially (compiler orders the intra-wave LDS accesses).
        if (kb <= lastA)
            strip_body(kb, rowbA, quad, l16, qfA, &Kb2[bcur][0], &Vb2[bcur][0],
                       Pw, ones, csc, oA, lsumA);
        if (kb <= lastB)
            strip_body(kb, rowbB, quad, l16, qfB, &Kb2[bcur][0], &Vb2[bcur][0],
                       Pw, ones, csc, oB, lsumB);

        bcur = (bcur == 2) ? 0 : bcur + 1;
        bpre = (bpre == 2) ? 0 : bpre + 1;
    }

    // epilogue: both strips
#pragma unroll
    for (int mt = 0; mt < 2; ++mt)
#pragma unroll
        for (int r = 0; r < 4; ++r) {
            float invA = 1.0f / lsumA[mt][r];
            float invB = 1.0f / lsumB[mt][r];
            int qrowA = rowbA + mt * 16 + quad * 4 + r;
            int qrowB = rowbB + mt * 16 + quad * 4 + r;
#pragma unroll
            for (int nt = 0; nt < 4; ++nt) {
                Yatt[((size_t)(bIdx * SEQ + qrowA) << 10) + h * 64 + nt * 16 + l16] =
                    f32_to_bf16(oA[mt][nt][r] * invA);
                Yatt[((size_t)(bIdx * SEQ + qrowB) << 10) + h * 64 + nt * 16 + l16] =
                    f32_to_bf16(oB[mt][nt][r] * invB);
            }
        }
}

// ---------------------------------------------------------------- launch
extern "C" void kernel_launch(void* const* d_in, const int* in_sizes, int n_in,
                              void* d_out, int out_size, void* d_ws, size_t ws_size,
                              hipStream_t stream) {
    const float* x = (const float*)d_in[0];
    const float* w_qkv = (const float*)d_in[1];
    const float* b_qkv = (const float*)d_in[2];
    const float* w_proj = (const float*)d_in[3];
    const float* b_proj = (const float*)d_in[4];
    float* out = (float*)d_out;

    char* ws = (char*)d_ws;
    unsigned short* xb     = (unsigned short*)(ws);                       // 16 MB
    unsigned short* wqkvT  = (unsigned short*)(ws + 16777216);            // 6 MB
    unsigned short* wprojT = (unsigned short*)(ws + 23068672);            // 2 MB
    unsigned short* Qb     = (unsigned short*)(ws + 25165824);            // 16 MB
    unsigned short* Kb     = (unsigned short*)(ws + 41943040);            // 16 MB
    unsigned short* Yatt   = (unsigned short*)(ws + 75497472);            // 16 MB
    unsigned short* Vt     = (unsigned short*)(ws + 92274688);            // 16 MB

    prep_kernel<<<dim3(384, 32), dim3(32, 8), 0, stream>>>(x, xb, w_qkv, wqkvT,
                                                           w_proj, wprojT);
    gemm_bt<0><<<dim3(24, 64), 256, 0, stream>>>(xb, wqkvT, b_qkv, nullptr, Qb, Kb, Vt,
                                                 MROWS, 3 * DMODEL, DMODEL);
    attn_kernel<<<dim3(64, 8), 256, 0, stream>>>(Qb, Kb, Vt, Yatt);
    gemm_bt<1><<<dim3(8, 64), 256, 0, stream>>>(Yatt, wprojT, b_proj, out, nullptr, nullptr,
                                                nullptr, MROWS, DMODEL, DMODEL);
}